// Round 11
// baseline (1182.570 us; speedup 1.0000x reference)
//
#include <hip/hip_runtime.h>
#include <hip/hip_bf16.h>
#include <math.h>

// ---------------------------------------------------------------------------
// LSTM_55327768708454:  T=128 B=256 D=512 H=1024 O=1
// Round 20: three independent low-risk changes on the r19 base:
//   (1) persist publish = wave-0 s_waitcnt vmcnt(0) + flag store (replaces
//       the post-store __syncthreads; all 64 h-stores are wave 0's, and the
//       aggregator's own __syncthreads still separates iterations). Isolated
//       this time (r14 bundled it with TC=64).
//   (2) prep_all mega-kernel: input cvt + W1 cvt + W_ih permute + W_hh cvt +
//       bias + h0-blocked + flag zero in ONE segmented launch.
//   (3) persist reads c0 directly on chunk 0 (cfin/cf split) - copy deleted.
//   gemm_bt8 (256^2 8-phase counted-vmcnt, r19) and aggregator: unchanged.
// ---------------------------------------------------------------------------

#define T_STEPS 128
#define BATCH   256
#define DIM     512
#define HID     1024
#define GATES   4096
#define FPAD    32   // ints per flag slot (128B)

typedef __attribute__((ext_vector_type(8))) short short8;
typedef __attribute__((ext_vector_type(4))) float f4;
typedef __attribute__((ext_vector_type(4))) int i4;

__device__ __forceinline__ short f2bf(float f) {
    union { float f; unsigned u; } x; x.f = f;
    unsigned r = (x.u + 0x7fffu + ((x.u >> 16) & 1u)) >> 16;
    return (short)r;
}
__device__ __forceinline__ float bf2f(short s) {
    union { unsigned u; float f; } x; x.u = ((unsigned)(unsigned short)s) << 16;
    return x.f;
}
__device__ __forceinline__ float sigm(float x) { return 1.f / (1.f + __expf(-x)); }
__device__ __forceinline__ float tanh_fast(float x) { return 2.f / (1.f + __expf(-2.f * x)) - 1.f; }

__device__ __forceinline__ void gll16(const void* g, void* l) {
    __builtin_amdgcn_global_load_lds(
        (const __attribute__((address_space(1))) void*)g,
        (__attribute__((address_space(3))) void*)l, 16, 0, 0);
}
__device__ __forceinline__ void store16_wt(void* p, i4 v) {
    asm volatile("global_store_dwordx4 %0, %1, off sc0 sc1"
                 :: "v"(p), "v"(v) : "memory");
}
__device__ __forceinline__ void cvt4(const float* src, short* dst, int i) {
    float4 v = ((const float4*)src)[i];
    union { short s[4]; long long ll; } r;
    r.s[0] = f2bf(v.x); r.s[1] = f2bf(v.y); r.s[2] = f2bf(v.z); r.s[3] = f2bf(v.w);
    ((long long*)dst)[i] = r.ll;
}

// ---------------- prep_all: every one-time prep job in one launch ----------
// segments (block ranges):
//   [0,16384)        inputs f32->bf16      (4194304 x 8B)
//   [16384,16896)    W1 f32->bf16          (131072)
//   [16896,20992)    W_ih row-permute      (4096 rows)
//   [20992,25088)    W_hh f32->bf16        (1048576)
//   [25088,25104)    bias sum+permute      (4096)
//   [25104,25360)    h0 -> blocked slot 0  (256 rows)
//   [25360,25872)    flags zero            (grid-stride, nflags ints)
#define PREP_BLOCKS 25872
__global__ __launch_bounds__(256) void prep_all(const float* __restrict__ inputs,
                                                const float* __restrict__ W1,
                                                const float* __restrict__ W_ih,
                                                const float* __restrict__ W_hh,
                                                const float* __restrict__ b_ih,
                                                const float* __restrict__ b_hh,
                                                const float* __restrict__ h0,
                                                short* __restrict__ inb,
                                                short* __restrict__ W1b,
                                                short* __restrict__ Wihb,
                                                short* __restrict__ Whhb,
                                                float* __restrict__ biasf,
                                                short* __restrict__ h0dst,
                                                int* __restrict__ flags,
                                                int nflags) {
    int bx = blockIdx.x;
    const int tid = threadIdx.x;
    if (bx < 16384) {                       // inputs cvt
        cvt4(inputs, inb, bx * 256 + tid);
    } else if ((bx -= 16384) < 512) {       // W1 cvt
        cvt4(W1, W1b, bx * 256 + tid);
    } else if ((bx -= 512) < 4096) {        // W_ih permute: out row hc*4+g
        int r = bx;
        int hc = r >> 2, g = r & 3;
        const float* src = W_ih + (size_t)(g * HID + hc) * HID;
        short* dst = Wihb + (size_t)r * HID;
        int c = tid * 4;
        float4 v = *(const float4*)&src[c];
        union { short s[4]; long long ll; } p;
        p.s[0] = f2bf(v.x); p.s[1] = f2bf(v.y); p.s[2] = f2bf(v.z); p.s[3] = f2bf(v.w);
        *(long long*)&dst[c] = p.ll;
    } else if ((bx -= 4096) < 4096) {       // W_hh cvt
        cvt4(W_hh, Whhb, bx * 256 + tid);
    } else if ((bx -= 4096) < 16) {         // bias sum+permute
        int r = bx * 256 + tid;
        int hc = r >> 2, g = r & 3;
        int src = g * HID + hc;
        biasf[r] = b_ih[src] + b_hh[src];
    } else if ((bx -= 16) < 256) {          // h0 -> blocked [slice][b][8]
        int b = bx, k0 = tid * 4;
        float4 v = *(const float4*)&h0[(size_t)b * HID + k0];
        union { short s[4]; long long ll; } p;
        p.s[0] = f2bf(v.x); p.s[1] = f2bf(v.y); p.s[2] = f2bf(v.z); p.s[3] = f2bf(v.w);
        *(long long*)&h0dst[(k0 >> 3) * (BATCH * 8) + b * 8 + (k0 & 7)] = p.ll;
    } else {                                // flags zero (512 blocks)
        bx -= 256;
        for (int i = bx * 256 + tid; i < nflags; i += 512 * 256)
            flags[i] = 0;
    }
}

// ---------------- gemm_bt8: 256^2 / BK=64 / 8-wave / 8-phase counted vmcnt ---
// C = A @ B^T + bias, opt relu. A:(M,K) B:(N,K) row-major bf16, C bf16.
// Requires M%256==0, N%256==0, K%128==0, grid (M/256, N/256), 512 threads.
// LDS: As/Bs[kt&1][256][64]; 16B slot s of row r holds global slot s^(r&7).
__global__ __launch_bounds__(512) void gemm_bt8(const short* __restrict__ A,
                                                const short* __restrict__ B,
                                                const float* __restrict__ bias,
                                                short* __restrict__ C,
                                                int M, int N, int K, int do_relu) {
    __shared__ __align__(16) short As[2][256 * 64];   // 64 KB
    __shared__ __align__(16) short Bs[2][256 * 64];   // 64 KB
    const int tid = threadIdx.x, w = tid >> 6, lane = tid & 63;
    const int wr = w >> 2, wc = w & 3;                // wave tile: 128 x 64

    // XCD-aware bijective block swizzle (m204 form)
    const int nwg = gridDim.x * gridDim.y;
    const int flat = blockIdx.y * gridDim.x + blockIdx.x;
    const int qq = nwg >> 3, rr = nwg & 7;
    const int xcd = flat & 7, oin = flat >> 3;
    const int swz = (xcd < rr ? xcd * (qq + 1) : rr * (qq + 1) + (xcd - rr) * qq) + oin;
    const int bm = (swz % gridDim.x) * 256, bn = (swz / gridDim.x) * 256;

    const int NT = K >> 6, NI = NT >> 1;

#define STG(P, L, bmn, kt, h)                                                  \
    if ((kt) < NT) {                                                           \
        _Pragma("unroll")                                                      \
        for (int s_ = 0; s_ < 2; ++s_) {                                       \
            int r0_ = (h) * 128 + s_ * 64 + w * 8;                             \
            int row_ = r0_ + (lane >> 3);                                      \
            int kof_ = ((lane & 7) ^ (row_ & 7)) * 8;                          \
            gll16(&P[(size_t)((bmn) + row_) * K + (kt) * 64 + kof_],           \
                  &L[(kt) & 1][r0_ * 64]);                                     \
        }                                                                      \
    }

#define LOADB(kt)                                                              \
    _Pragma("unroll")                                                          \
    for (int nf = 0; nf < 4; ++nf)                                             \
        _Pragma("unroll")                                                      \
        for (int ks = 0; ks < 2; ++ks) {                                       \
            int rb_ = wc * 64 + nf * 16 + (lane & 15);                         \
            int sb_ = (ks * 4 + (lane >> 4)) ^ (rb_ & 7);                      \
            bfr[nf][ks] = *(const short8*)&Bs[(kt) & 1][rb_ * 64 + sb_ * 8];   \
        }

#define LOADA(kt, q)                                                           \
    _Pragma("unroll")                                                          \
    for (int mi = 0; mi < 2; ++mi)                                             \
        _Pragma("unroll")                                                      \
        for (int ks = 0; ks < 2; ++ks) {                                       \
            int ra_ = wr * 128 + ((q) * 2 + mi) * 16 + (lane & 15);            \
            int sa_ = (ks * 4 + (lane >> 4)) ^ (ra_ & 7);                      \
            af[mi][ks] = *(const short8*)&As[(kt) & 1][ra_ * 64 + sa_ * 8];    \
        }

#define MFMAQ(q)                                                               \
    __builtin_amdgcn_s_setprio(1);                                             \
    _Pragma("unroll")                                                          \
    for (int mi = 0; mi < 2; ++mi)                                             \
        _Pragma("unroll")                                                      \
        for (int nf = 0; nf < 4; ++nf)                                         \
            _Pragma("unroll")                                                  \
            for (int ks = 0; ks < 2; ++ks)                                     \
                acc[(q) * 2 + mi][nf] = __builtin_amdgcn_mfma_f32_16x16x32_bf16( \
                    af[mi][ks], bfr[nf][ks], acc[(q) * 2 + mi][nf], 0, 0, 0);  \
    __builtin_amdgcn_s_setprio(0);                                             \
    __builtin_amdgcn_sched_barrier(0);

#define VM4 asm volatile("s_waitcnt vmcnt(4)" ::: "memory");
#define VM0 asm volatile("s_waitcnt vmcnt(0)" ::: "memory");
#define BAR __builtin_amdgcn_s_barrier();

    f4 acc[8][4] = {};

    // prologue: A(0) h0,h1; B(0) h0,h1; B(1) h0,h1
    STG(A, As, bm, 0, 0) STG(A, As, bm, 0, 1)
    STG(B, Bs, bn, 0, 0) STG(B, Bs, bn, 0, 1)
    STG(B, Bs, bn, 1, 0) STG(B, Bs, bn, 1, 1)

    for (int it = 0; it < NI; ++it) {
        const int kt0 = 2 * it, kt1 = 2 * it + 1;
        const int lastit = (it + 1 == NI);
        short8 bfr[4][2], af[2][2];

        // ---- K-tile kt0: phases 0..3 ----
        VM4 BAR
        LOADB(kt0) LOADA(kt0, 0)
        STG(A, As, bm, kt1, 0)
        MFMAQ(0)
        BAR
        LOADA(kt0, 1)
        STG(A, As, bm, kt1, 1)
        MFMAQ(1)
        BAR
        LOADA(kt0, 2)
        STG(B, Bs, bn, kt0 + 2, 0)
        MFMAQ(2)
        BAR
        LOADA(kt0, 3)
        STG(B, Bs, bn, kt0 + 2, 1)
        MFMAQ(3)

        // ---- K-tile kt1: phases 4..7 ----
        if (lastit) { VM0 } else { VM4 }
        BAR
        LOADB(kt1) LOADA(kt1, 0)
        STG(A, As, bm, kt0 + 2, 0)
        MFMAQ(0)
        BAR
        LOADA(kt1, 1)
        STG(A, As, bm, kt0 + 2, 1)
        MFMAQ(1)
        BAR
        LOADA(kt1, 2)
        STG(B, Bs, bn, kt1 + 2, 0)
        MFMAQ(2)
        BAR
        LOADA(kt1, 3)
        STG(B, Bs, bn, kt1 + 2, 1)
        MFMAQ(3)
    }
#undef STG
#undef LOADB
#undef LOADA
#undef MFMAQ
#undef VM4
#undef VM0
#undef BAR

    const int lc = lane & 15, lr = (lane >> 4) * 4;
#pragma unroll
    for (int mf = 0; mf < 8; ++mf) {
#pragma unroll
        for (int nf = 0; nf < 4; ++nf) {
            int col = bn + wc * 64 + nf * 16 + lc;
            float bv = bias[col];
#pragma unroll
            for (int r = 0; r < 4; ++r) {
                int row = bm + wr * 128 + mf * 16 + lr + r;
                float v = acc[mf][nf][r] + bv;
                if (do_relu) v = fmaxf(v, 0.f);
                C[(size_t)row * N + col] = f2bf(v);
            }
        }
    }
}

// ---------------- persistent recurrence over TC steps ----------------
// 512 blocks (2/CU): bg = bx>>7 (64 batch rows), cg = bx&127 (8 h-cols).
// hist slots are BLOCKED: [slice(=k/8)][b][8], slice cg owned by block (.,cg).
// K-loop: A-loads pipelined 3 groups deep; MFMA clusters in s_setprio.
// Aggregator barrier (r7 topology). Publish = wave-0 vmcnt(0) drain
// (all 64 h-stores are wave 0's; no block-wide barrier needed).
__global__ __launch_bounds__(256) void lstm_persist(const short* __restrict__ Whh,
                                                    const short* __restrict__ xgc,
                                                    short* __restrict__ hist,
                                                    const float* __restrict__ cfin,
                                                    float* __restrict__ cf,
                                                    float* __restrict__ hT,
                                                    float* __restrict__ cT,
                                                    int* __restrict__ flags,
                                                    int* __restrict__ go,
                                                    int TC, int last) {
    __shared__ __align__(16) short Bf[32768];   // 64 KB W_hh strip fragments
    __shared__ __align__(16) short Ht[512];     // 1 KB h-tile staging (64 rows x 8 cols)
    const int tid = threadIdx.x, w = tid >> 6, lane = tid & 63;
    const int bg = blockIdx.x >> 7, cg = blockIdx.x & 127;
    const int bb = bg * 64, hc0 = cg * 8;
    const int hcl = lane & 7, gp = (lane >> 3) & 1, q = lane >> 4;

    // ---- fill W_hh strip fragments once ----
#pragma unroll
    for (int i = 0; i < 16; ++i) {
        int p = w * 16 + i;
        int c = p >> 1, t = p & 1;
        gll16(&Whh[(size_t)((t * 2 + gp) * HID + hc0 + hcl) * HID + c * 32 + q * 8],
              &Bf[p * 512]);
    }

    // ---- c-state into registers ----
    const int rowb = bb + w * 16 + q * 4 + gp * 2;       // rows rowb, rowb+1
    float creg[2];
#pragma unroll
    for (int e = 0; e < 2; ++e)
        creg[e] = cfin[(size_t)(rowb + e) * HID + hc0 + hcl];

    __syncthreads();   // strip ready

    // prime xg for step 0
    unsigned long long xw[2], xwn[2];
#pragma unroll
    for (int e = 0; e < 2; ++e)
        xw[e] = *(const unsigned long long*)&xgc[(size_t)(rowb + e) * GATES
                                                 + (hc0 + hcl) * 4];

#define ISSUE_A(buf, g)                                                        \
    _Pragma("unroll")                                                          \
    for (int i = 0; i < 8; ++i)                                                \
        buf[i] = *(const short8*)(abase + (size_t)((g) * 8 + i) * astr);

#define COMPUTE_A(buf, g)                                                      \
    __builtin_amdgcn_s_setprio(1);                                             \
    _Pragma("unroll")                                                          \
    for (int i = 0; i < 8; ++i) {                                              \
        short8 b0 = *(const short8*)&Bf[(((g) * 8 + i) * 2 + 0) * 512 + lane * 8]; \
        short8 b1 = *(const short8*)&Bf[(((g) * 8 + i) * 2 + 1) * 512 + lane * 8]; \
        acc0 = __builtin_amdgcn_mfma_f32_16x16x32_bf16(buf[i], b0, acc0, 0, 0, 0); \
        acc1 = __builtin_amdgcn_mfma_f32_16x16x32_bf16(buf[i], b1, acc1, 0, 0, 0); \
    }                                                                          \
    __builtin_amdgcn_s_setprio(0);

    for (int tt = 0; tt < TC; ++tt) {
        // ---- prefetch next step's xg ----
        if (tt + 1 < TC) {
#pragma unroll
            for (int e = 0; e < 2; ++e)
                xwn[e] = *(const unsigned long long*)&xgc[(size_t)((tt + 1) * BATCH + rowb + e) * GATES
                                                          + (hc0 + hcl) * 4];
        }

        // ---- K-loop: A from blocked hist (slice = c*4+q), B resident in LDS,
        //      3-group-deep explicit A prefetch pipeline ----
        const short* abase = hist + (size_t)tt * BATCH * HID
                           + (size_t)q * (BATCH * 8) + (size_t)(bb + w * 16 + (lane & 15)) * 8;
        const size_t astr = (size_t)4 * (BATCH * 8);
        f4 acc0 = {}, acc1 = {};
        short8 ab0[8], ab1[8], ab2[8];
        ISSUE_A(ab0, 0)
        ISSUE_A(ab1, 1)
        ISSUE_A(ab2, 2)
        COMPUTE_A(ab0, 0)
        ISSUE_A(ab0, 3)
        COMPUTE_A(ab1, 1)
        COMPUTE_A(ab2, 2)
        COMPUTE_A(ab0, 3)

        // ---- gate exchange across lane^8 ----
        float p0[4], p1[4];
#pragma unroll
        for (int r = 0; r < 4; ++r) {
            p0[r] = __shfl_xor(acc0[r], 8);
            p1[r] = __shfl_xor(acc1[r], 8);
        }

        int glast = last && (tt == TC - 1);
#pragma unroll
        for (int e = 0; e < 2; ++e) {
            int r = gp * 2 + e;
            size_t b = rowb + e;
            float gi = gp ? p0[r] : acc0[r];
            float gf = gp ? acc0[r] : p0[r];
            float gg = gp ? p1[r] : acc1[r];
            float go_ = gp ? acc1[r] : p1[r];
            gi += bf2f((short)(xw[e] & 0xffff));
            gf += bf2f((short)((xw[e] >> 16) & 0xffff));
            gg += bf2f((short)((xw[e] >> 32) & 0xffff));
            go_ += bf2f((short)((xw[e] >> 48) & 0xffff));
            float si = sigm(gi), sf = sigm(gf), tg = tanh_fast(gg), so = sigm(go_);
            float cn = sf * creg[e] + si * tg;
            float hv = so * tanh_fast(cn);
            creg[e] = cn;
            Ht[(w * 16 + q * 4 + gp * 2 + e) * 8 + hcl] = f2bf(hv);
            if (glast) {
                hT[b * HID + hc0 + hcl] = hv;
                cT[b * HID + hc0 + hcl] = cn;
            }
        }
        xw[0] = xwn[0]; xw[1] = xwn[1];
        __syncthreads();   // Ht complete

        // ---- packed h stores: 64 x 16B CONTIGUOUS (8 full lines, wave 0 only) ----
        short* hn = hist + (size_t)(tt + 1) * BATCH * HID
                  + (size_t)cg * (BATCH * 8) + (size_t)bb * 8;
        if (tid < 64)
            store16_wt(&hn[tid * 8], *(const i4*)&Ht[tid * 8]);

        // ---- publish (wave-0 vmcnt drain) + aggregator barrier (r7) ----
        if (tt < TC - 1) {
            const int base = (tt * 4 + bg) * 128 * FPAD;
            if (w == 0) {
                // all 64 h-stores above are wave 0's; same-wave vmcnt(0)
                // orders them before the flag store. Waves 1-3 keep their
                // in-flight prefetches and proceed to the aggregator wait.
                asm volatile("s_waitcnt vmcnt(0)" ::: "memory");
                if (tid == 0)
                    __hip_atomic_store(&flags[base + cg * FPAD], 1,
                                       __ATOMIC_RELAXED, __HIP_MEMORY_SCOPE_AGENT);
            }
            if (cg == 0) {
                if (tid < 128) {
                    while (__hip_atomic_load(&flags[base + tid * FPAD],
                                             __ATOMIC_RELAXED, __HIP_MEMORY_SCOPE_AGENT) == 0)
                        __builtin_amdgcn_s_sleep(1);
                }
                __syncthreads();
                if (tid == 0)
                    __hip_atomic_store(&go[(tt * 4 + bg) * FPAD], 1,
                                       __ATOMIC_RELAXED, __HIP_MEMORY_SCOPE_AGENT);
            } else {
                if (tid == 0) {
                    while (__hip_atomic_load(&go[(tt * 4 + bg) * FPAD],
                                             __ATOMIC_RELAXED, __HIP_MEMORY_SCOPE_AGENT) == 0)
                        __builtin_amdgcn_s_sleep(1);
                }
                __syncthreads();
            }
        }
    }

#undef ISSUE_A
#undef COMPUTE_A

    // ---- write back c-state for next chunk ----
#pragma unroll
    for (int e = 0; e < 2; ++e)
        cf[(size_t)(rowb + e) * HID + hc0 + hcl] = creg[e];
}

// ---------------- output head over the FULL h history (blocked layout) ----------------
__global__ __launch_bounds__(256) void out_head(const short* __restrict__ hs,
                                                const float* __restrict__ Wout,
                                                const float* __restrict__ bout,
                                                float* __restrict__ out) {
    int row = blockIdx.x * 4 + (threadIdx.x >> 6);   // tt*256 + b
    int lane = threadIdx.x & 63;
    int tt = row >> 8, b = row & 255;
    const short* sb = hs + (size_t)(tt + 1) * BATCH * HID + b * 8;   // slot tt+1
    const float2* w2 = (const float2*)Wout;
    float s = 0.f;
#pragma unroll
    for (int j = 0; j < 8; ++j) {
        int m = j * 64 + lane;                       // pair index 0..511, k=2m
        int pk = *(const int*)&sb[(size_t)(m >> 2) * (BATCH * 8) + 2 * (m & 3)];
        float2 wv = w2[m];
        union { unsigned u; float f; } lo, hi;
        lo.u = ((unsigned)pk) << 16;
        hi.u = ((unsigned)pk) & 0xffff0000u;
        s += lo.f * wv.x + hi.f * wv.y;
    }
#pragma unroll
    for (int off = 32; off; off >>= 1) s += __shfl_down(s, off);
    if (lane == 0) out[row] = s + bout[0];
}

// ---------------------------------------------------------------------------
extern "C" void kernel_launch(void* const* d_in, const int* in_sizes, int n_in,
                              void* d_out, int out_size, void* d_ws, size_t ws_size,
                              hipStream_t stream) {
    const float* inputs = (const float*)d_in[0];
    const float* h0     = (const float*)d_in[1];
    const float* c0     = (const float*)d_in[2];
    const float* W1     = (const float*)d_in[3];
    const float* b1     = (const float*)d_in[4];
    const float* W_ih   = (const float*)d_in[5];
    const float* W_hh   = (const float*)d_in[6];
    const float* b_ih   = (const float*)d_in[7];
    const float* b_hh   = (const float*)d_in[8];
    const float* W_out  = (const float*)d_in[9];
    const float* b_out  = (const float*)d_in[10];

    float* out = (float*)d_out;
    float* hT  = out + (size_t)T_STEPS * BATCH;
    float* cT  = hT + (size_t)BATCH * HID;

    char* base = (char*)d_ws;
    size_t off = 0;
    auto alloc = [&](size_t bytes) -> char* {
        char* q = base + off;
        off += (bytes + 255) & ~(size_t)255;
        return q;
    };
    short* W1b   = (short*)alloc((size_t)HID * DIM * 2);
    short* Wihb  = (short*)alloc((size_t)GATES * HID * 2);      // row-permuted
    short* Whhb  = (short*)alloc((size_t)GATES * HID * 2);      // plain layout
    float* biasf = (float*)alloc((size_t)GATES * 4);            // permuted
    float* cf    = (float*)alloc((size_t)BATCH * HID * 4);
    int*   flags = (int*)alloc((size_t)T_STEPS * 4 * 128 * FPAD * 4);  // 8 MB
    int*   go    = (int*)alloc((size_t)T_STEPS * 4 * FPAD * 4);        // 64 KB (contiguous after flags)

    short* xb_a  = (short*)alloc((size_t)T_STEPS * BATCH * HID * 2);   // 67 MB
    short* hhist = (short*)alloc((size_t)(T_STEPS + 1) * BATCH * HID * 2); // 64.5 MB

    // ---- ws-adaptive xg path ----
    size_t xg_all_bytes = (size_t)T_STEPS * BATCH * GATES * 2;          // 268 MB
    size_t inb_bytes    = (size_t)T_STEPS * BATCH * DIM * 2;            // 33.5 MB
    int ALLX = (ws_size - off) >= (xg_all_bytes + 4096);
    short *xgb = nullptr, *inb_a = nullptr;
    int TC = 32;
    if (ALLX) {
        xgb   = (short*)alloc(xg_all_bytes);
        inb_a = xgb;                             // aliased; dead before xgb written
    } else {
        size_t per_c = (size_t)TC * BATCH * GATES * 2;
        while (TC > 1 && off + (per_c > inb_bytes ? per_c : inb_bytes) + 4096 > ws_size) {
            TC >>= 1;
            per_c = (size_t)TC * BATCH * GATES * 2;
        }
        size_t region = per_c > inb_bytes ? per_c : inb_bytes;
        xgb   = (short*)alloc(region);
        inb_a = xgb;                             // aliased; dead before xgb written
    }

    // ---- ALL one-time prep in a single launch ----
    prep_all<<<PREP_BLOCKS, 256, 0, stream>>>(
        inputs, W1, W_ih, W_hh, b_ih, b_hh, h0,
        inb_a, W1b, Wihb, Whhb, biasf, hhist, flags,
        T_STEPS * 4 * 128 * FPAD + T_STEPS * 4 * FPAD);

    // ---- first-layer GEMM for ALL timesteps (+ all-xg if ws allows) ----
    {
        int Ma = T_STEPS * BATCH;                       // 32768
        gemm_bt8<<<dim3(Ma / 256, HID / 256), 512, 0, stream>>>(
            inb_a, W1b, b1, xb_a, Ma, HID, DIM, 1);     // grid 128x4 = 512
        if (ALLX) {
            gemm_bt8<<<dim3(Ma / 256, GATES / 256), 512, 0, stream>>>(
                xb_a, Wihb, biasf, xgb, Ma, GATES, HID, 0);   // grid 128x16
        }
    }

    // ---- chunked recurrence over in-place h history ----
    for (int t0 = 0; t0 < T_STEPS; t0 += TC) {
        int last = (t0 + TC >= T_STEPS);
        const short* xgc;
        if (ALLX) {
            xgc = xgb + (size_t)t0 * BATCH * GATES;
        } else {
            int Mc = TC * BATCH;
            gemm_bt8<<<dim3(Mc / 256, GATES / 256), 512, 0, stream>>>(
                xb_a + (size_t)t0 * BATCH * HID, Wihb, biasf, xgb,
                Mc, GATES, HID, 0);                      // grid 32x16 = 512
            xgc = xgb;
        }

        lstm_persist<<<512, 256, 0, stream>>>(Whhb, xgc,
                                              hhist + (size_t)t0 * BATCH * HID,
                                              (t0 == 0) ? c0 : cf, cf, hT, cT,
                                              flags + (size_t)t0 * 4 * 128 * FPAD,
                                              go + (size_t)t0 * 4 * FPAD,
                                              TC, last);
    }

    // ---- output head once over the full history ----
    out_head<<<T_STEPS * BATCH / 4, 256, 0, stream>>>(hhist, W_out, b_out, out);
}